// Round 6
// baseline (127.899 us; speedup 1.0000x reference)
//
#include <hip/hip_runtime.h>
#include <stdint.h>

#define NT 2048
#define DT 128

typedef __bf16 bf16x8 __attribute__((ext_vector_type(8)));
typedef __bf16 bf16x4 __attribute__((ext_vector_type(4)));
typedef float  f32x16 __attribute__((ext_vector_type(16)));
typedef uint32_t u32x4 __attribute__((ext_vector_type(4)));

static __device__ __forceinline__ uint32_t pk2(float lo, float hi) {
    union { __bf16 h[2]; uint32_t u; } un;
    un.h[0] = (__bf16)lo; un.h[1] = (__bf16)hi;
    return un.u;
}

// v_permlane32_swap_b32: x' = {x.lo32, y.lo32}, y' = {x.hi32, y.hi32}.
// s_nop guards for VALU->permlane and permlane->MFMA hazard windows.
static __device__ __forceinline__ void lane32_swap(uint32_t& x, uint32_t& y) {
    asm("s_nop 0\n\tv_permlane32_swap_b32 %0, %1\n\ts_nop 1"
        : "+v"(x), "+v"(y));
}

// ============================================================================
// prep2: convert Q,K,V fp32 into MFMA-FRAGMENT-ORDER bf16 buffers so every
// fragment load downstream is one coalesced 1KB wave-load.
//   Qf[b][c][k][l][j] = Q[b][d=16k+8*(l>>5)+j][n=32c+(l&31)]     (4 MB)
//   Kf[b][mc][k][l][j] = K[b][d=16k+8*(l>>5)+j][m=32mc+(l&31)]   (4 MB)
//   Vf[b][c][vc][kk][l][j] = V[b][v=32vc+(l&31)][n=32c+16kk+8*(l>>5)+j] (4 MB)
// ============================================================================
__global__ __launch_bounds__(256)
void prep2(const float* __restrict__ Q, const float* __restrict__ K,
           const float* __restrict__ V,
           __bf16* __restrict__ Qf, __bf16* __restrict__ Kf, __bf16* __restrict__ Vf)
{
    const int bid = blockIdx.x;
    const int t   = threadIdx.x;
    if (bid < 512) {
        __shared__ float ls[128][65];
        const int which = bid >> 8;            // 0=Q, 1=K
        const float* src = which ? K : Q;
        __bf16*      dst = which ? Kf : Qf;
        const int idx = bid & 255;
        const int b   = idx >> 5;              // 0..7
        const int ct  = idx & 31;              // 64-wide n/m tile
        const int n0  = ct * 64;
        const float* sb = src + (size_t)b * DT * NT;
        #pragma unroll
        for (int rr = 0; rr < 8; ++rr) {
            const int d = (t >> 4) + 16 * rr;
            const float4 v4 = *(const float4*)(sb + (size_t)d * NT + n0 + 4 * (t & 15));
            ls[d][4 * (t & 15) + 0] = v4.x;
            ls[d][4 * (t & 15) + 1] = v4.y;
            ls[d][4 * (t & 15) + 2] = v4.z;
            ls[d][4 * (t & 15) + 3] = v4.w;
        }
        __syncthreads();
        const int l  = t & 63;
        const int kq = t >> 6;                 // 0..3
        const int lq = l >> 5, l31 = l & 31;
        #pragma unroll
        for (int c = 0; c < 2; ++c) {
            #pragma unroll
            for (int kh = 0; kh < 2; ++kh) {
                const int k = kq + 4 * kh;
                bf16x8 f;
                #pragma unroll
                for (int j = 0; j < 8; ++j)
                    f[j] = (__bf16)ls[16 * k + 8 * lq + j][32 * c + l31];
                *(bf16x8*)(dst + ((size_t)((b * 64 + 2 * ct + c) * 8 + k)) * 512 + l * 8) = f;
            }
        }
    } else {
        const int idx = bid - 512;             // 0..255
        const int b   = idx >> 5;
        const int cg  = idx & 31;
        const int l   = t & 63;
        const int vc  = t >> 6;                // 0..3
        const int lq  = l >> 5, l31 = l & 31;
        const float* vsrc = V + (size_t)b * DT * NT;
        #pragma unroll
        for (int ci = 0; ci < 2; ++ci) {
            const int c = 2 * cg + ci;
            #pragma unroll
            for (int kk = 0; kk < 2; ++kk) {
                const float* p = vsrc + (size_t)(32 * vc + l31) * NT + 32 * c + 16 * kk + 8 * lq;
                const float4 x = *(const float4*)p;
                const float4 y = *(const float4*)(p + 4);
                bf16x8 f;
                f[0] = (__bf16)x.x; f[1] = (__bf16)x.y; f[2] = (__bf16)x.z; f[3] = (__bf16)x.w;
                f[4] = (__bf16)y.x; f[5] = (__bf16)y.y; f[6] = (__bf16)y.z; f[7] = (__bf16)y.w;
                *(bf16x8*)(Vf + ((size_t)((b * 64 + c) * 4 + vc) * 2 + kk) * 512 + l * 8) = f;
            }
        }
    }
}

// ============================================================================
// sig_attn7: kills the 4x per-wave Q/V fragment-load redundancy (the L1/TA
// operand-delivery bound of attn6) by staging each 64-n chunk ONCE per block
// in double-buffered LDS (2 x 32KB: frags 0..15 = Q, 16..31 = V, each 1KB
// lane-linear), reg-staged with async split: issue 8 global_load_dwordx4 for
// chunk it+1 at body top, compute chunk it from LDS (ds_read_b128,
// conflict-free), ds_write + ONE barrier per chunk (8 total).
// Per-chunk compute keeps the proven attn5/6 pipeline: GEMM1(sub0) and
// GEMM1(sub1) issued before sigmoid(sub0) so MFMA overlaps VALU; C->B
// exchange via v_permlane32_swap_b32 (HW-proven in attn6).
//   mfma_f32_32x32x16_bf16 C/D: col=lane&31, row=(reg&3)+8*(reg>>2)+4*(lane>>5)
// ============================================================================
__global__ __launch_bounds__(256, 2)
void sig_attn7(const __bf16* __restrict__ Qf, const __bf16* __restrict__ Kf,
               const __bf16* __restrict__ Vf, float* __restrict__ wsp)
{
    __shared__ __align__(16) __bf16 buf[2][16384];   // 2 x 32KB

    const int t   = threadIdx.x;
    const int w   = t >> 6;       // wave 0..3 -> m-column
    const int l   = t & 63;
    const int lq  = l >> 5;
    const int l31 = l & 31;

    const int bid = blockIdx.x;
    const int b   = bid & 7;             // XCD-pinned batch
    const int mt  = (bid >> 3) & 15;
    const int ns  = bid >> 7;            // 0..3

    const int mrow = 32 * w + l31;       // local m within 128-tile

    // ---- K B-frags for this wave's m-column (per-wave distinct, stay global)
    const __bf16* kfp = Kf + ((size_t)((b * 64 + 4 * mt + w) * 8)) * 512 + l * 8;
    bf16x8 kf[8];
    #pragma unroll
    for (int k = 0; k < 8; ++k) kf[k] = *(const bf16x8*)(kfp + (size_t)k * 512);

    // chunk = 64 n = 16KB of Q frags + 16KB of V frags, both contiguous
    const int c_base = ns * 16;
    const __bf16* qbase = Qf + ((size_t)(b * 64 + c_base) * 8) * 512;
    const __bf16* vbase = Vf + ((size_t)(b * 64 + c_base) * 8) * 512;

    f32x16 oacc[4];
    #pragma unroll
    for (int tv = 0; tv < 4; ++tv)
        #pragma unroll
        for (int r = 0; r < 16; ++r) oacc[tv][r] = 0.0f;

    // ---- staging: 32KB/chunk = 2048 x 16B units; thread t owns units p*256+t.
    // p<4 -> Q region (units 0..1023), p>=4 -> V region (units 1024..2047).
    float4 ld[8];
    auto issue = [&](int it_) {
        #pragma unroll
        for (int p = 0; p < 8; ++p) {
            const int u = p * 256 + t;
            const __bf16* src = (p < 4)
                ? qbase + (size_t)it_ * 8192 + (size_t)u * 8
                : vbase + (size_t)it_ * 8192 + (size_t)(u - 1024) * 8;
            ld[p] = *(const float4*)src;
        }
    };
    auto store = [&](int cb) {
        #pragma unroll
        for (int p = 0; p < 8; ++p) {
            const int u = p * 256 + t;
            *(float4*)&buf[cb][u * 8] = ld[p];
        }
    };

    // ---- prologue: stage chunk 0
    issue(0);
    store(0);
    __syncthreads();

    #pragma unroll 1
    for (int it = 0; it < 8; ++it) {
        const int cb = it & 1;
        __bf16* B = buf[cb];

        // -- async-issue chunk it+1 global loads (consumed at body end)
        if (it < 7) issue(it + 1);

        // -- GEMM1 sub0 and sub1 (MFMAs issued before any sigmoid VALU)
        bf16x8 qf[8];
        f32x16 s0, s1;
        #pragma unroll
        for (int r = 0; r < 16; ++r) { s0[r] = 0.0f; s1[r] = 0.0f; }
        #pragma unroll
        for (int k = 0; k < 8; ++k) qf[k] = *(const bf16x8*)&B[(0 * 8 + k) * 512 + l * 8];
        #pragma unroll
        for (int k = 0; k < 8; ++k)
            s0 = __builtin_amdgcn_mfma_f32_32x32x16_bf16(qf[k], kf[k], s0, 0, 0, 0);
        #pragma unroll
        for (int k = 0; k < 8; ++k) qf[k] = *(const bf16x8*)&B[(1 * 8 + k) * 512 + l * 8];
        #pragma unroll
        for (int k = 0; k < 8; ++k)
            s1 = __builtin_amdgcn_mfma_f32_32x32x16_bf16(qf[k], kf[k], s1, 0, 0, 0);

        // -- sub0: sigmoid + permlane exchange + GEMM2 (s1 MFMAs retire under it)
        #pragma unroll
        for (int sub = 0; sub < 2; ++sub) {
            const f32x16& S = sub ? s1 : s0;
            float p[16];
            #pragma unroll
            for (int r = 0; r < 16; ++r) {
                const float e = __expf(S[r] * -0.08838834764831845f);
                p[r] = __builtin_amdgcn_rcpf(1.0f + e);
            }
            uint32_t e0 = pk2(p[0],  p[1]),  e1 = pk2(p[2],  p[3]);
            uint32_t e2 = pk2(p[4],  p[5]),  e3 = pk2(p[6],  p[7]);
            uint32_t g0 = pk2(p[8],  p[9]),  g1 = pk2(p[10], p[11]);
            uint32_t g2 = pk2(p[12], p[13]), g3 = pk2(p[14], p[15]);
            lane32_swap(e0, e2);
            lane32_swap(e1, e3);
            lane32_swap(g0, g2);
            lane32_swap(g1, g3);
            u32x4 f0, f1;
            f0[0] = e0; f0[1] = e1; f0[2] = e2; f0[3] = e3;
            f1[0] = g0; f1[1] = g1; f1[2] = g2; f1[3] = g3;
            const bf16x8 bs0 = __builtin_bit_cast(bf16x8, f0);
            const bf16x8 bs1 = __builtin_bit_cast(bf16x8, f1);

            bf16x8 av[8];
            #pragma unroll
            for (int q = 0; q < 8; ++q)
                av[q] = *(const bf16x8*)&B[(16 + sub * 8 + q) * 512 + l * 8];
            #pragma unroll
            for (int tv = 0; tv < 4; ++tv) {
                oacc[tv] = __builtin_amdgcn_mfma_f32_32x32x16_bf16(av[2 * tv],     bs0, oacc[tv], 0, 0, 0);
                oacc[tv] = __builtin_amdgcn_mfma_f32_32x32x16_bf16(av[2 * tv + 1], bs1, oacc[tv], 0, 0, 0);
            }
        }

        // -- land chunk it+1 into the other buffer, one barrier per chunk
        if (it < 7) store(cb ^ 1);
        __syncthreads();
    }

    // ---- epilogue: per-block partial [v 128][m 128] (reduce4 layout)
    float* wsb = wsp + (size_t)bid * 16384;
    #pragma unroll
    for (int tv = 0; tv < 4; ++tv) {
        #pragma unroll
        for (int r = 0; r < 16; ++r) {
            const int v = 32 * tv + (r & 3) + 8 * (r >> 2) + 4 * lq;
            wsb[v * 128 + mrow] = oacc[tv][r];
        }
    }
}

// out[o] = sum over 4 n-splits of ws partials; float4 per thread, fully coalesced
__global__ __launch_bounds__(256)
void reduce4(const float4* __restrict__ ws, float4* __restrict__ out)
{
    const int i = blockIdx.x * 256 + threadIdx.x;
    const int o = i * 4;
    const int m_glob = o & 2047;
    const int vb     = o >> 11;
    const int v      = vb & 127;
    const int bb     = vb >> 7;
    const int mt     = m_glob >> 7;
    const int m      = m_glob & 127;
    const size_t base = ((size_t)(bb + 8 * mt) * 16384 + (size_t)v * 128 + m) >> 2;
    const size_t strd = 524288;
    float4 a = ws[base];
    float4 c = ws[base + strd];
    float4 d = ws[base + 2 * strd];
    float4 e = ws[base + 3 * strd];
    float4 r;
    r.x = a.x + c.x + d.x + e.x;
    r.y = a.y + c.y + d.y + e.y;
    r.z = a.z + c.z + d.z + e.z;
    r.w = a.w + c.w + d.w + e.w;
    out[i] = r;
}

// ============================================================================
// v1 kernel kept verbatim as fallback for small-ws harnesses
// ============================================================================
template <int WSMODE>
__global__ __launch_bounds__(512, 4)
void sig_attn(const float* __restrict__ Q, const float* __restrict__ K,
              const float* __restrict__ V, float* __restrict__ outp)
{
    __shared__ __align__(16) __bf16 Qs[64 * 128];
    __shared__ __align__(16) __bf16 Ss[128 * 64];
    __shared__ __align__(16) __bf16 Vs[2][128 * 64];

    const int t   = threadIdx.x;
    const int w   = t >> 6;
    const int l   = t & 63;
    const int lq  = l >> 5;
    const int l31 = l & 31;
    const int wm  = w & 3;
    const int wn  = w >> 2;

    const int bid    = blockIdx.x;
    const int b      = bid & 7;
    const int mt     = (bid >> 3) & 15;
    const int ns     = bid >> 7;
    const int m_blk  = mt * 128;
    const int n_base = ns * 512;

    const float* Qb = Q + (size_t)b * DT * NT;
    const float* Kb = K + (size_t)b * DT * NT;
    const float* Vb = V + (size_t)b * DT * NT;

    const int mrow = 32 * wm + l31;

    bf16x8 kf[8];
    #pragma unroll
    for (int half = 0; half < 2; ++half) {
        float tmp[4][8];
        #pragma unroll
        for (int k2 = 0; k2 < 4; ++k2)
            #pragma unroll
            for (int j = 0; j < 8; ++j)
                tmp[k2][j] = Kb[(size_t)((half * 4 + k2) * 16 + lq * 8 + j) * NT + m_blk + mrow];
        #pragma unroll
        for (int k2 = 0; k2 < 4; ++k2) {
            bf16x8 f;
            #pragma unroll
            for (int j = 0; j < 8; ++j) f[j] = (__bf16)tmp[k2][j];
            kf[half * 4 + k2] = f;
        }
    }

    f32x16 oacc[2];
    #pragma unroll
    for (int tv = 0; tv < 2; ++tv)
        #pragma unroll
        for (int r = 0; r < 16; ++r)
            oacc[tv][r] = 0.0f;

    float qp[16];
    #pragma unroll
    for (int r = 0; r < 2; ++r)
        #pragma unroll
        for (int j = 0; j < 8; ++j)
            qp[r * 8 + j] = Qb[(size_t)(64 * r + 8 * w + j) * NT + n_base + l];
    float4 vp[4];
    #pragma unroll
    for (int p = 0; p < 4; ++p)
        vp[p] = *(const float4*)(Vb + (size_t)(p * 32 + (t >> 4)) * NT + n_base + 4 * (t & 15));

    for (int it = 0; it < 8; ++it) {
        __bf16* Vbuf = Vs[it & 1];

        #pragma unroll
        for (int r = 0; r < 2; ++r) {
            bf16x8 pk;
            #pragma unroll
            for (int j = 0; j < 8; ++j) pk[j] = (__bf16)qp[r * 8 + j];
            *(bf16x8*)&Qs[l * 128 + ((8 * r + w) ^ (l & 15)) * 8] = pk;
        }
        #pragma unroll
        for (int p = 0; p < 4; ++p) {
            const int v  = p * 32 + (t >> 4);
            const int ng = t & 15;
            bf16x4 pk;
            pk[0] = (__bf16)vp[p].x;
            pk[1] = (__bf16)vp[p].y;
            pk[2] = (__bf16)vp[p].z;
            pk[3] = (__bf16)vp[p].w;
            *(bf16x4*)&Vbuf[v * 64 + ((ng >> 1) ^ (v & 7)) * 8 + 4 * (ng & 1)] = pk;
        }
        __syncthreads();

        const int n0n = n_base + ((it + 1) & 7) * 64;
        #pragma unroll
        for (int r = 0; r < 2; ++r)
            #pragma unroll
            for (int j = 0; j < 8; ++j)
                qp[r * 8 + j] = Qb[(size_t)(64 * r + 8 * w + j) * NT + n0n + l];
        #pragma unroll
        for (int p = 0; p < 4; ++p)
            vp[p] = *(const float4*)(Vb + (size_t)(p * 32 + (t >> 4)) * NT + n0n + 4 * (t & 15));

        f32x16 sacc;
        #pragma unroll
        for (int r = 0; r < 16; ++r) sacc[r] = 0.0f;
        const int nrow = 32 * wn + l31;
        #pragma unroll
        for (int k = 0; k < 8; ++k) {
            const bf16x8 af =
                *(const bf16x8*)&Qs[nrow * 128 + ((2 * k + lq) ^ (nrow & 15)) * 8];
            sacc = __builtin_amdgcn_mfma_f32_32x32x16_bf16(af, kf[k], sacc, 0, 0, 0);
        }

        #pragma unroll
        for (int g = 0; g < 4; ++g) {
            bf16x4 pk;
            #pragma unroll
            for (int rr = 0; rr < 4; ++rr) {
                const float x = sacc[4 * g + rr];
                const float e = __expf(x * -0.08838834764831845f);
                pk[rr] = (__bf16)__builtin_amdgcn_rcpf(1.0f + e);
            }
            *(bf16x4*)&Ss[mrow * 64 + ((4 * wn + g) ^ (mrow & 7)) * 8 + 4 * lq] = pk;
        }
        __syncthreads();

        #pragma unroll
        for (int k = 0; k < 4; ++k) {
            const int sw = 2 * k + lq;
            const bf16x8 av0 =
                *(const bf16x8*)&Vbuf[(64 * wn + l31) * 64 + (sw ^ (l31 & 7)) * 8];
            const bf16x8 av1 =
                *(const bf16x8*)&Vbuf[(64 * wn + 32 + l31) * 64 + (sw ^ (l31 & 7)) * 8];
            const bf16x8 bs =
                *(const bf16x8*)&Ss[mrow * 64 + (sw ^ (mrow & 7)) * 8];
            oacc[0] = __builtin_amdgcn_mfma_f32_32x32x16_bf16(av0, bs, oacc[0], 0, 0, 0);
            oacc[1] = __builtin_amdgcn_mfma_f32_32x32x16_bf16(av1, bs, oacc[1], 0, 0, 0);
        }
    }

    if (WSMODE == 0) {
        float* wsb = outp + (size_t)bid * 16384;
        #pragma unroll
        for (int tv = 0; tv < 2; ++tv) {
            #pragma unroll
            for (int r = 0; r < 16; ++r) {
                const int v = 64 * wn + 32 * tv + (r & 3) + 8 * (r >> 2) + 4 * lq;
                wsb[v * 128 + mrow] = oacc[tv][r];
            }
        }
    } else {
        float* Ob = outp + (size_t)b * DT * NT;
        #pragma unroll
        for (int tv = 0; tv < 2; ++tv) {
            #pragma unroll
            for (int r = 0; r < 16; ++r) {
                const int v = 64 * wn + 32 * tv + (r & 3) + 8 * (r >> 2) + 4 * lq;
                atomicAdd(&Ob[(size_t)v * NT + m_blk + mrow], oacc[tv][r]);
            }
        }
    }
}

extern "C" void kernel_launch(void* const* d_in, const int* in_sizes, int n_in,
                              void* d_out, int out_size, void* d_ws, size_t ws_size,
                              hipStream_t stream) {
    (void)in_sizes; (void)n_in;
    const float* Q = (const float*)d_in[0];
    const float* K = (const float*)d_in[1];
    const float* V = (const float*)d_in[2];
    const size_t PART  = (size_t)512 * 16384 * 4;          // 33.5 MB fp32 partials
    const size_t FRAGB = (size_t)2097152 * 2;              // 4 MB per operand buffer
    if (ws_size >= PART + 3 * FRAGB) {                     // 45.6 MB (ws is 256 MiB)
        __bf16* Qf = (__bf16*)((char*)d_ws + PART);
        __bf16* Kf = Qf + 2097152;
        __bf16* Vf = Kf + 2097152;
        prep2<<<dim3(768), dim3(256), 0, stream>>>(Q, K, V, Qf, Kf, Vf);
        sig_attn7<<<dim3(512), dim3(256), 0, stream>>>(Qf, Kf, Vf, (float*)d_ws);
        reduce4<<<dim3(2048), dim3(256), 0, stream>>>((const float4*)d_ws, (float4*)d_out);
    } else if (ws_size >= PART) {
        sig_attn<0><<<dim3(512), dim3(512), 0, stream>>>(Q, K, V, (float*)d_ws);
        reduce4<<<dim3(2048), dim3(256), 0, stream>>>((const float4*)d_ws, (float4*)d_out);
    } else {
        hipMemsetAsync(d_out, 0, (size_t)out_size * sizeof(float), stream);
        sig_attn<1><<<dim3(512), dim3(512), 0, stream>>>(Q, K, V, (float*)d_out);
    }
}

// Round 7
// 104.767 us; speedup vs baseline: 1.2208x; 1.2208x over previous
//
#include <hip/hip_runtime.h>
#include <stdint.h>

#define NT 2048
#define DT 128

typedef __bf16 bf16x8 __attribute__((ext_vector_type(8)));
typedef __bf16 bf16x4 __attribute__((ext_vector_type(4)));
typedef float  f32x16 __attribute__((ext_vector_type(16)));
typedef uint32_t u32x4 __attribute__((ext_vector_type(4)));

static __device__ __forceinline__ uint32_t pk2(float lo, float hi) {
    union { __bf16 h[2]; uint32_t u; } un;
    un.h[0] = (__bf16)lo; un.h[1] = (__bf16)hi;
    return un.u;
}

// v_permlane32_swap_b32: x' = {x.lo32, y.lo32}, y' = {x.hi32, y.hi32}.
// s_nop guards for VALU->permlane and permlane->MFMA hazard windows.
static __device__ __forceinline__ void lane32_swap(uint32_t& x, uint32_t& y) {
    asm("s_nop 0\n\tv_permlane32_swap_b32 %0, %1\n\ts_nop 1"
        : "+v"(x), "+v"(y));
}

// ============================================================================
// prep2: convert Q,K,V fp32 into MFMA-FRAGMENT-ORDER bf16 buffers so every
// fragment load downstream is one coalesced 1KB wave-load.
//   Qf[b][c][k][l][j] = Q[b][d=16k+8*(l>>5)+j][n=32c+(l&31)]     (4 MB)
//   Kf[b][mc][k][l][j] = K[b][d=16k+8*(l>>5)+j][m=32mc+(l&31)]   (4 MB)
//   Vf[b][c][vc][kk][l][j] = V[b][v=32vc+(l&31)][n=32c+16kk+8*(l>>5)+j] (4 MB)
// ============================================================================
__global__ __launch_bounds__(256)
void prep2(const float* __restrict__ Q, const float* __restrict__ K,
           const float* __restrict__ V,
           __bf16* __restrict__ Qf, __bf16* __restrict__ Kf, __bf16* __restrict__ Vf)
{
    const int bid = blockIdx.x;
    const int t   = threadIdx.x;
    if (bid < 512) {
        __shared__ float ls[128][65];
        const int which = bid >> 8;            // 0=Q, 1=K
        const float* src = which ? K : Q;
        __bf16*      dst = which ? Kf : Qf;
        const int idx = bid & 255;
        const int b   = idx >> 5;              // 0..7
        const int ct  = idx & 31;              // 64-wide n/m tile
        const int n0  = ct * 64;
        const float* sb = src + (size_t)b * DT * NT;
        #pragma unroll
        for (int rr = 0; rr < 8; ++rr) {
            const int d = (t >> 4) + 16 * rr;
            const float4 v4 = *(const float4*)(sb + (size_t)d * NT + n0 + 4 * (t & 15));
            ls[d][4 * (t & 15) + 0] = v4.x;
            ls[d][4 * (t & 15) + 1] = v4.y;
            ls[d][4 * (t & 15) + 2] = v4.z;
            ls[d][4 * (t & 15) + 3] = v4.w;
        }
        __syncthreads();
        const int l  = t & 63;
        const int kq = t >> 6;                 // 0..3
        const int lq = l >> 5, l31 = l & 31;
        #pragma unroll
        for (int c = 0; c < 2; ++c) {
            #pragma unroll
            for (int kh = 0; kh < 2; ++kh) {
                const int k = kq + 4 * kh;
                bf16x8 f;
                #pragma unroll
                for (int j = 0; j < 8; ++j)
                    f[j] = (__bf16)ls[16 * k + 8 * lq + j][32 * c + l31];
                *(bf16x8*)(dst + ((size_t)((b * 64 + 2 * ct + c) * 8 + k)) * 512 + l * 8) = f;
            }
        }
    } else {
        const int idx = bid - 512;             // 0..255
        const int b   = idx >> 5;
        const int cg  = idx & 31;
        const int l   = t & 63;
        const int vc  = t >> 6;                // 0..3
        const int lq  = l >> 5, l31 = l & 31;
        const float* vsrc = V + (size_t)b * DT * NT;
        #pragma unroll
        for (int ci = 0; ci < 2; ++ci) {
            const int c = 2 * cg + ci;
            #pragma unroll
            for (int kk = 0; kk < 2; ++kk) {
                const float* p = vsrc + (size_t)(32 * vc + l31) * NT + 32 * c + 16 * kk + 8 * lq;
                const float4 x = *(const float4*)p;
                const float4 y = *(const float4*)(p + 4);
                bf16x8 f;
                f[0] = (__bf16)x.x; f[1] = (__bf16)x.y; f[2] = (__bf16)x.z; f[3] = (__bf16)x.w;
                f[4] = (__bf16)y.x; f[5] = (__bf16)y.y; f[6] = (__bf16)y.z; f[7] = (__bf16)y.w;
                *(bf16x8*)(Vf + ((size_t)((b * 64 + c) * 4 + vc) * 2 + kk) * 512 + l * 8) = f;
            }
        }
    }
}

// ============================================================================
// sig_attn8: attn7's block-level LDS sharing (kills the 4x per-wave Q/V
// fragment redundancy through L1), re-implemented with ZERO-VGPR staging:
// __builtin_amdgcn_global_load_lds width=16 DMAs each 64-n chunk (32KB:
// frags 0..15 = Q, 16..31 = V, each 1KB lane-linear) straight into
// double-buffered LDS. 8 instrs/wave/chunk issued for chunk it+1 at body
// top (full compute phase of flight time; the vmcnt(0) drain at the barrier
// is then ~free); ONE barrier per chunk (8 total).
// No ld[] VGPR array -> no scratch spill (attn7's 90MB WRITE_SIZE bug).
// Compute body is attn7's verbatim (HW-verified): GEMM1 sub0+sub1 MFMAs
// issued before sigmoid VALU; C->B exchange via v_permlane32_swap_b32.
//   mfma_f32_32x32x16_bf16 C/D: col=lane&31, row=(reg&3)+8*(reg>>2)+4*(lane>>5)
// ============================================================================
__global__ __launch_bounds__(256, 2)
void sig_attn8(const __bf16* __restrict__ Qf, const __bf16* __restrict__ Kf,
               const __bf16* __restrict__ Vf, float* __restrict__ wsp)
{
    __shared__ __align__(16) __bf16 buf[2][16384];   // 2 x 32KB

    const int t   = threadIdx.x;
    const int w   = t >> 6;       // wave 0..3 -> m-column
    const int l   = t & 63;
    const int lq  = l >> 5;
    const int l31 = l & 31;

    const int bid = blockIdx.x;
    const int b   = bid & 7;             // XCD-pinned batch
    const int mt  = (bid >> 3) & 15;
    const int ns  = bid >> 7;            // 0..3

    const int mrow = 32 * w + l31;       // local m within 128-tile

    // ---- K B-frags for this wave's m-column (per-wave distinct, stay global)
    const __bf16* kfp = Kf + ((size_t)((b * 64 + 4 * mt + w) * 8)) * 512 + l * 8;
    bf16x8 kf[8];
    #pragma unroll
    for (int k = 0; k < 8; ++k) kf[k] = *(const bf16x8*)(kfp + (size_t)k * 512);

    // chunk = 64 n: 16KB Q frags + 16KB V frags, both linear in fragment order
    const int c_base = ns * 16;
    const __bf16* qbase = Qf + ((size_t)(b * 64 + c_base) * 8) * 512;
    const __bf16* vbase = Vf + ((size_t)(b * 64 + c_base) * 8) * 512;

    f32x16 oacc[4];
    #pragma unroll
    for (int tv = 0; tv < 4; ++tv)
        #pragma unroll
        for (int r = 0; r < 16; ++r) oacc[tv][r] = 0.0f;

    // ---- staging: frag f (0..31) = 1KB; wave w DMAs frags 8w..8w+7.
    // LDS dest is wave-uniform base (+ lane*16 implicit); global src per-lane.
    auto stage = [&](int it_, int cb) {
        #pragma unroll
        for (int p = 0; p < 8; ++p) {
            const int f = 8 * w + p;
            const __bf16* src = (f < 16)
                ? qbase + (size_t)it_ * 8192 + (size_t)f * 512 + l * 8
                : vbase + (size_t)it_ * 8192 + (size_t)(f - 16) * 512 + l * 8;
            __builtin_amdgcn_global_load_lds(
                (const __attribute__((address_space(1))) uint32_t*)src,
                (__attribute__((address_space(3))) uint32_t*)&buf[cb][f * 512],
                16, 0, 0);
        }
    };

    // ---- prologue: stage chunk 0 (barrier's vmcnt(0) drain covers completion)
    stage(0, 0);
    __syncthreads();

    #pragma unroll 1
    for (int it = 0; it < 8; ++it) {
        const int cb = it & 1;
        const __bf16* B = buf[cb];

        // -- DMA chunk it+1 into the other buffer (in flight across compute)
        if (it < 7) stage(it + 1, cb ^ 1);

        // -- GEMM1 sub0 and sub1 (all MFMAs issued before any sigmoid VALU)
        bf16x8 qf[8];
        f32x16 s0, s1;
        #pragma unroll
        for (int r = 0; r < 16; ++r) { s0[r] = 0.0f; s1[r] = 0.0f; }
        #pragma unroll
        for (int k = 0; k < 8; ++k) qf[k] = *(const bf16x8*)&B[(0 * 8 + k) * 512 + l * 8];
        #pragma unroll
        for (int k = 0; k < 8; ++k)
            s0 = __builtin_amdgcn_mfma_f32_32x32x16_bf16(qf[k], kf[k], s0, 0, 0, 0);
        #pragma unroll
        for (int k = 0; k < 8; ++k) qf[k] = *(const bf16x8*)&B[(1 * 8 + k) * 512 + l * 8];
        #pragma unroll
        for (int k = 0; k < 8; ++k)
            s1 = __builtin_amdgcn_mfma_f32_32x32x16_bf16(qf[k], kf[k], s1, 0, 0, 0);

        // -- per sub-chunk: sigmoid + permlane exchange + GEMM2
        #pragma unroll
        for (int sub = 0; sub < 2; ++sub) {
            const f32x16& S = sub ? s1 : s0;
            float p[16];
            #pragma unroll
            for (int r = 0; r < 16; ++r) {
                const float e = __expf(S[r] * -0.08838834764831845f);
                p[r] = __builtin_amdgcn_rcpf(1.0f + e);
            }
            uint32_t e0 = pk2(p[0],  p[1]),  e1 = pk2(p[2],  p[3]);
            uint32_t e2 = pk2(p[4],  p[5]),  e3 = pk2(p[6],  p[7]);
            uint32_t g0 = pk2(p[8],  p[9]),  g1 = pk2(p[10], p[11]);
            uint32_t g2 = pk2(p[12], p[13]), g3 = pk2(p[14], p[15]);
            lane32_swap(e0, e2);
            lane32_swap(e1, e3);
            lane32_swap(g0, g2);
            lane32_swap(g1, g3);
            u32x4 f0, f1;
            f0[0] = e0; f0[1] = e1; f0[2] = e2; f0[3] = e3;
            f1[0] = g0; f1[1] = g1; f1[2] = g2; f1[3] = g3;
            const bf16x8 bs0 = __builtin_bit_cast(bf16x8, f0);
            const bf16x8 bs1 = __builtin_bit_cast(bf16x8, f1);

            bf16x8 av[8];
            #pragma unroll
            for (int q = 0; q < 8; ++q)
                av[q] = *(const bf16x8*)&B[(16 + sub * 8 + q) * 512 + l * 8];
            #pragma unroll
            for (int tv = 0; tv < 4; ++tv) {
                oacc[tv] = __builtin_amdgcn_mfma_f32_32x32x16_bf16(av[2 * tv],     bs0, oacc[tv], 0, 0, 0);
                oacc[tv] = __builtin_amdgcn_mfma_f32_32x32x16_bf16(av[2 * tv + 1], bs1, oacc[tv], 0, 0, 0);
            }
        }

        // one barrier per chunk: drains the chunk-(it+1) DMA (long in flight)
        // and fences buffer reuse for the next iteration's stage
        __syncthreads();
    }

    // ---- epilogue: per-block partial [v 128][m 128] (reduce4 layout)
    float* wsb = wsp + (size_t)bid * 16384;
    #pragma unroll
    for (int tv = 0; tv < 4; ++tv) {
        #pragma unroll
        for (int r = 0; r < 16; ++r) {
            const int v = 32 * tv + (r & 3) + 8 * (r >> 2) + 4 * lq;
            wsb[v * 128 + mrow] = oacc[tv][r];
        }
    }
}

// out[o] = sum over 4 n-splits of ws partials; float4 per thread, fully coalesced
__global__ __launch_bounds__(256)
void reduce4(const float4* __restrict__ ws, float4* __restrict__ out)
{
    const int i = blockIdx.x * 256 + threadIdx.x;
    const int o = i * 4;
    const int m_glob = o & 2047;
    const int vb     = o >> 11;
    const int v      = vb & 127;
    const int bb     = vb >> 7;
    const int mt     = m_glob >> 7;
    const int m      = m_glob & 127;
    const size_t base = ((size_t)(bb + 8 * mt) * 16384 + (size_t)v * 128 + m) >> 2;
    const size_t strd = 524288;
    float4 a = ws[base];
    float4 c = ws[base + strd];
    float4 d = ws[base + 2 * strd];
    float4 e = ws[base + 3 * strd];
    float4 r;
    r.x = a.x + c.x + d.x + e.x;
    r.y = a.y + c.y + d.y + e.y;
    r.z = a.z + c.z + d.z + e.z;
    r.w = a.w + c.w + d.w + e.w;
    out[i] = r;
}

// ============================================================================
// v1 kernel kept verbatim as fallback for small-ws harnesses
// ============================================================================
template <int WSMODE>
__global__ __launch_bounds__(512, 4)
void sig_attn(const float* __restrict__ Q, const float* __restrict__ K,
              const float* __restrict__ V, float* __restrict__ outp)
{
    __shared__ __align__(16) __bf16 Qs[64 * 128];
    __shared__ __align__(16) __bf16 Ss[128 * 64];
    __shared__ __align__(16) __bf16 Vs[2][128 * 64];

    const int t   = threadIdx.x;
    const int w   = t >> 6;
    const int l   = t & 63;
    const int lq  = l >> 5;
    const int l31 = l & 31;
    const int wm  = w & 3;
    const int wn  = w >> 2;

    const int bid    = blockIdx.x;
    const int b      = bid & 7;
    const int mt     = (bid >> 3) & 15;
    const int ns     = bid >> 7;
    const int m_blk  = mt * 128;
    const int n_base = ns * 512;

    const float* Qb = Q + (size_t)b * DT * NT;
    const float* Kb = K + (size_t)b * DT * NT;
    const float* Vb = V + (size_t)b * DT * NT;

    const int mrow = 32 * wm + l31;

    bf16x8 kf[8];
    #pragma unroll
    for (int half = 0; half < 2; ++half) {
        float tmp[4][8];
        #pragma unroll
        for (int k2 = 0; k2 < 4; ++k2)
            #pragma unroll
            for (int j = 0; j < 8; ++j)
                tmp[k2][j] = Kb[(size_t)((half * 4 + k2) * 16 + lq * 8 + j) * NT + m_blk + mrow];
        #pragma unroll
        for (int k2 = 0; k2 < 4; ++k2) {
            bf16x8 f;
            #pragma unroll
            for (int j = 0; j < 8; ++j) f[j] = (__bf16)tmp[k2][j];
            kf[half * 4 + k2] = f;
        }
    }

    f32x16 oacc[2];
    #pragma unroll
    for (int tv = 0; tv < 2; ++tv)
        #pragma unroll
        for (int r = 0; r < 16; ++r)
            oacc[tv][r] = 0.0f;

    float qp[16];
    #pragma unroll
    for (int r = 0; r < 2; ++r)
        #pragma unroll
        for (int j = 0; j < 8; ++j)
            qp[r * 8 + j] = Qb[(size_t)(64 * r + 8 * w + j) * NT + n_base + l];
    float4 vp[4];
    #pragma unroll
    for (int p = 0; p < 4; ++p)
        vp[p] = *(const float4*)(Vb + (size_t)(p * 32 + (t >> 4)) * NT + n_base + 4 * (t & 15));

    for (int it = 0; it < 8; ++it) {
        __bf16* Vbuf = Vs[it & 1];

        #pragma unroll
        for (int r = 0; r < 2; ++r) {
            bf16x8 pk;
            #pragma unroll
            for (int j = 0; j < 8; ++j) pk[j] = (__bf16)qp[r * 8 + j];
            *(bf16x8*)&Qs[l * 128 + ((8 * r + w) ^ (l & 15)) * 8] = pk;
        }
        #pragma unroll
        for (int p = 0; p < 4; ++p) {
            const int v  = p * 32 + (t >> 4);
            const int ng = t & 15;
            bf16x4 pk;
            pk[0] = (__bf16)vp[p].x;
            pk[1] = (__bf16)vp[p].y;
            pk[2] = (__bf16)vp[p].z;
            pk[3] = (__bf16)vp[p].w;
            *(bf16x4*)&Vbuf[v * 64 + ((ng >> 1) ^ (v & 7)) * 8 + 4 * (ng & 1)] = pk;
        }
        __syncthreads();

        const int n0n = n_base + ((it + 1) & 7) * 64;
        #pragma unroll
        for (int r = 0; r < 2; ++r)
            #pragma unroll
            for (int j = 0; j < 8; ++j)
                qp[r * 8 + j] = Qb[(size_t)(64 * r + 8 * w + j) * NT + n0n + l];
        #pragma unroll
        for (int p = 0; p < 4; ++p)
            vp[p] = *(const float4*)(Vb + (size_t)(p * 32 + (t >> 4)) * NT + n0n + 4 * (t & 15));

        f32x16 sacc;
        #pragma unroll
        for (int r = 0; r < 16; ++r) sacc[r] = 0.0f;
        const int nrow = 32 * wn + l31;
        #pragma unroll
        for (int k = 0; k < 8; ++k) {
            const bf16x8 af =
                *(const bf16x8*)&Qs[nrow * 128 + ((2 * k + lq) ^ (nrow & 15)) * 8];
            sacc = __builtin_amdgcn_mfma_f32_32x32x16_bf16(af, kf[k], sacc, 0, 0, 0);
        }

        #pragma unroll
        for (int g = 0; g < 4; ++g) {
            bf16x4 pk;
            #pragma unroll
            for (int rr = 0; rr < 4; ++rr) {
                const float x = sacc[4 * g + rr];
                const float e = __expf(x * -0.08838834764831845f);
                pk[rr] = (__bf16)__builtin_amdgcn_rcpf(1.0f + e);
            }
            *(bf16x4*)&Ss[mrow * 64 + ((4 * wn + g) ^ (mrow & 7)) * 8 + 4 * lq] = pk;
        }
        __syncthreads();

        #pragma unroll
        for (int k = 0; k < 4; ++k) {
            const int sw = 2 * k + lq;
            const bf16x8 av0 =
                *(const bf16x8*)&Vbuf[(64 * wn + l31) * 64 + (sw ^ (l31 & 7)) * 8];
            const bf16x8 av1 =
                *(const bf16x8*)&Vbuf[(64 * wn + 32 + l31) * 64 + (sw ^ (l31 & 7)) * 8];
            const bf16x8 bs =
                *(const bf16x8*)&Ss[mrow * 64 + (sw ^ (mrow & 7)) * 8];
            oacc[0] = __builtin_amdgcn_mfma_f32_32x32x16_bf16(av0, bs, oacc[0], 0, 0, 0);
            oacc[1] = __builtin_amdgcn_mfma_f32_32x32x16_bf16(av1, bs, oacc[1], 0, 0, 0);
        }
    }

    if (WSMODE == 0) {
        float* wsb = outp + (size_t)bid * 16384;
        #pragma unroll
        for (int tv = 0; tv < 2; ++tv) {
            #pragma unroll
            for (int r = 0; r < 16; ++r) {
                const int v = 64 * wn + 32 * tv + (r & 3) + 8 * (r >> 2) + 4 * lq;
                wsb[v * 128 + mrow] = oacc[tv][r];
            }
        }
    } else {
        float* Ob = outp + (size_t)b * DT * NT;
        #pragma unroll
        for (int tv = 0; tv < 2; ++tv) {
            #pragma unroll
            for (int r = 0; r < 16; ++r) {
                const int v = 64 * wn + 32 * tv + (r & 3) + 8 * (r >> 2) + 4 * lq;
                atomicAdd(&Ob[(size_t)v * NT + m_blk + mrow], oacc[tv][r]);
            }
        }
    }
}

extern "C" void kernel_launch(void* const* d_in, const int* in_sizes, int n_in,
                              void* d_out, int out_size, void* d_ws, size_t ws_size,
                              hipStream_t stream) {
    (void)in_sizes; (void)n_in;
    const float* Q = (const float*)d_in[0];
    const float* K = (const float*)d_in[1];
    const float* V = (const float*)d_in[2];
    const size_t PART  = (size_t)512 * 16384 * 4;          // 33.5 MB fp32 partials
    const size_t FRAGB = (size_t)2097152 * 2;              // 4 MB per operand buffer
    if (ws_size >= PART + 3 * FRAGB) {                     // 45.6 MB (ws is 256 MiB)
        __bf16* Qf = (__bf16*)((char*)d_ws + PART);
        __bf16* Kf = Qf + 2097152;
        __bf16* Vf = Kf + 2097152;
        prep2<<<dim3(768), dim3(256), 0, stream>>>(Q, K, V, Qf, Kf, Vf);
        sig_attn8<<<dim3(512), dim3(256), 0, stream>>>(Qf, Kf, Vf, (float*)d_ws);
        reduce4<<<dim3(2048), dim3(256), 0, stream>>>((const float4*)d_ws, (float4*)d_out);
    } else if (ws_size >= PART) {
        sig_attn<0><<<dim3(512), dim3(512), 0, stream>>>(Q, K, V, (float*)d_ws);
        reduce4<<<dim3(2048), dim3(256), 0, stream>>>((const float4*)d_ws, (float4*)d_out);
    } else {
        hipMemsetAsync(d_out, 0, (size_t)out_size * sizeof(float), stream);
        sig_attn<1><<<dim3(512), dim3(512), 0, stream>>>(Q, K, V, (float*)d_out);
    }
}